// Round 1
// baseline (521.427 us; speedup 1.0000x reference)
//
#include <hip/hip_runtime.h>

// Problem: x (32, 64, 224, 224) fp32. out (32, 64) fp32, every row identical:
// out[b][c] = sigmoid( mean over (batch, H, W) of x[:, c, :, :] ).
//
// Pure HBM-bound single-pass reduction: 411 MB in, 8 KB out.
// Phase 1: one block per (b,c) plane (2048 planes, 50176 floats each),
//          float4 coalesced loads, wave64 shuffle reduce -> ws[plane].
// Phase 2: per-channel sum of 32 plane partials, sigmoid, broadcast.
// Deterministic (no atomics), no workspace initialization required.

#define PLANE_ELEMS 50176           // 224*224
#define PLANE_F4    12544           // 50176/4
#define THREADS     256
#define F4_PER_THR  49              // 12544/256
#define N_PLANES    2048            // 32*64
#define INV_N       (1.0f / 1605632.0f)  // 1/(32*224*224)

__global__ __launch_bounds__(THREADS) void plane_sum_kernel(
    const float* __restrict__ x, float* __restrict__ plane_sums) {
    const int plane = blockIdx.x;  // = b*64 + c
    const float4* p = reinterpret_cast<const float4*>(x) + (size_t)plane * PLANE_F4;

    float s = 0.f;
#pragma unroll
    for (int i = 0; i < F4_PER_THR; ++i) {
        float4 v = p[threadIdx.x + i * THREADS];
        s += (v.x + v.y) + (v.z + v.w);
    }

    // wave-64 butterfly reduce
#pragma unroll
    for (int off = 32; off > 0; off >>= 1)
        s += __shfl_down(s, off, 64);

    __shared__ float acc[4];
    const int lane = threadIdx.x & 63;
    const int wave = threadIdx.x >> 6;
    if (lane == 0) acc[wave] = s;
    __syncthreads();
    if (threadIdx.x == 0)
        plane_sums[plane] = (acc[0] + acc[1]) + (acc[2] + acc[3]);
}

__global__ __launch_bounds__(256) void finalize_kernel(
    const float* __restrict__ plane_sums, float* __restrict__ out) {
    const int t = blockIdx.x * blockDim.x + threadIdx.x;  // 0..2047
    if (t >= N_PLANES) return;
    const int c = t & 63;
    float s = 0.f;
#pragma unroll
    for (int b = 0; b < 32; ++b) s += plane_sums[b * 64 + c];
    const float m = s * INV_N;
    out[t] = 1.0f / (1.0f + expf(-m));
}

extern "C" void kernel_launch(void* const* d_in, const int* in_sizes, int n_in,
                              void* d_out, int out_size, void* d_ws, size_t ws_size,
                              hipStream_t stream) {
    const float* x = (const float*)d_in[0];
    float* out = (float*)d_out;
    float* ws = (float*)d_ws;  // 2048 floats of plane partial sums

    plane_sum_kernel<<<N_PLANES, THREADS, 0, stream>>>(x, ws);
    finalize_kernel<<<(N_PLANES + 255) / 256, 256, 0, stream>>>(ws, out);
}

// Round 2
// 486.424 us; speedup vs baseline: 1.0720x; 1.0720x over previous
//
#include <hip/hip_runtime.h>

// x: (32, 64, 224, 224) fp32 -> out (32, 64) fp32, all rows identical:
//   out[b][c] = sigmoid( mean_{batch,H,W} x[:, c, :, :] )
//
// 411 MB single-pass HBM-bound reduction. Floor = 411 MB / 6.3 TB/s ~= 65 us.
// Phase 1: one 256-thread block per (b,c) plane (2048 blocks = 8/CU),
//          nontemporal float4 loads, unroll capped at 7 so VGPRs stay <= 64
//          (__launch_bounds__(256,8) -> 8 waves/SIMD for stream latency hiding),
//          wave64 shuffle reduce -> ws[plane]. Deterministic, no atomics.
// Phase 2: single block sums 32 partials/channel, sigmoid, broadcasts 2048 outs.

typedef float f32x4 __attribute__((ext_vector_type(4)));

#define PLANE_F4  12544              // (224*224)/4 float4 per plane
#define THREADS   256
#define N_PLANES  2048               // 32*64
#define INV_N     (1.0f / 1605632.0f)  // 1/(32*224*224)

__global__ __launch_bounds__(THREADS, 8) void plane_sum_kernel(
    const f32x4* __restrict__ x, float* __restrict__ plane_sums) {
    const int plane = blockIdx.x;  // = b*64 + c
    const f32x4* p = x + (size_t)plane * PLANE_F4 + threadIdx.x;

    float s0 = 0.f, s1 = 0.f;
#pragma unroll 7
    for (int i = 0; i < 49; ++i) {          // 12544 / 256 = 49
        f32x4 v = __builtin_nontemporal_load(p + i * THREADS);
        s0 += v.x + v.y;
        s1 += v.z + v.w;
    }
    float s = s0 + s1;

#pragma unroll
    for (int off = 32; off > 0; off >>= 1)
        s += __shfl_down(s, off, 64);

    __shared__ float acc[4];
    if ((threadIdx.x & 63) == 0) acc[threadIdx.x >> 6] = s;
    __syncthreads();
    if (threadIdx.x == 0)
        plane_sums[plane] = (acc[0] + acc[1]) + (acc[2] + acc[3]);
}

__global__ __launch_bounds__(256) void finalize_kernel(
    const float* __restrict__ plane_sums, float* __restrict__ out) {
    __shared__ float ch[64];
    const int t = threadIdx.x;
    if (t < 64) {
        float s = 0.f;
#pragma unroll
        for (int b = 0; b < 32; ++b) s += plane_sums[b * 64 + t];
        const float m = s * INV_N;
        ch[t] = 1.0f / (1.0f + expf(-m));
    }
    __syncthreads();
#pragma unroll
    for (int i = 0; i < 8; ++i) {
        const int o = t + i * 256;          // 0..2047
        out[o] = ch[o & 63];
    }
}

extern "C" void kernel_launch(void* const* d_in, const int* in_sizes, int n_in,
                              void* d_out, int out_size, void* d_ws, size_t ws_size,
                              hipStream_t stream) {
    const f32x4* x = (const f32x4*)d_in[0];
    float* out = (float*)d_out;
    float* ws = (float*)d_ws;  // 2048 plane partial sums

    plane_sum_kernel<<<N_PLANES, THREADS, 0, stream>>>(x, ws);
    finalize_kernel<<<1, 256, 0, stream>>>(ws, out);
}